// Round 12
// baseline (410.582 us; speedup 1.0000x reference)
//
#include <hip/hip_runtime.h>
#include <hip/hip_bf16.h>
#include <hip/hip_cooperative_groups.h>

namespace cg = cooperative_groups;

// Problem constants
#define H 1024
#define NHEAD 16
#define HDIM 64
#define SEQ 2048
#define BATCH 2
#define M_TOT (BATCH * SEQ) // 4096 tokens
#define NQKV 3072           // fused QKV output cols
#define NCOOP 512           // persistent coop grid (2 blocks/CU — safe margin)

typedef __attribute__((ext_vector_type(8))) short bf16x8; // 8 bf16 = 4 VGPRs (MFMA A/B frag)
typedef __attribute__((ext_vector_type(4))) float f32x4;  // MFMA C/D frag

// (1/sqrt(HDIM)) * log2(e), folded into Q at the QKV-GEMM epilogue
#define C2_SCALE 0.18033688f

__device__ __forceinline__ unsigned short f2bf(float f) {
  union { float f; unsigned int u; } a;
  a.f = f;
  unsigned int u = a.u;
  return (unsigned short)((u + 0x7fffu + ((u >> 16) & 1u)) >> 16); // RNE
}

__device__ __forceinline__ unsigned int pkbf(float a, float b) {
  union { __hip_bfloat162 h; unsigned int u; } cv;
  cv.h = __float22bfloat162_rn(float2{a, b});
  return cv.u;
}

__device__ __forceinline__ float fast_exp2(float x) {
#if defined(__has_builtin) && __has_builtin(__builtin_amdgcn_exp2f)
  return __builtin_amdgcn_exp2f(x);
#else
  return exp2f(x);
#endif
}

// async global->LDS, 16B per lane. LDS dest is wave-uniform base + lane*16.
typedef const __attribute__((address_space(1))) void* gas1_t;
typedef __attribute__((address_space(3))) void* las3_t;
__device__ __forceinline__ void gload16(const void* g, void* l) {
  __builtin_amdgcn_global_load_lds((gas1_t)(unsigned long long)g,
                                   (las3_t)(unsigned int)(unsigned long long)l,
                                   16, 0, 0);
}

// ---------------------------------------------------------------------------
// LN row / weight-cast tile bodies (shared by coop phase 0 and fallback).
// ---------------------------------------------------------------------------
__device__ __forceinline__ void lncast_tile(int v, float* red, const float* __restrict__ x,
                                            const float* __restrict__ gamma,
                                            const float* __restrict__ beta,
                                            unsigned short* __restrict__ xn,
                                            const float* __restrict__ w0,
                                            const float* __restrict__ w1,
                                            const float* __restrict__ w2,
                                            const float* __restrict__ w3,
                                            unsigned short* __restrict__ wdst) {
  const int t = threadIdx.x;
  if (v >= M_TOT) {
    const int cb = v - M_TOT;
    const int y = cb >> 10;
    const float* s = (y == 0) ? w0 : (y == 1) ? w1 : (y == 2) ? w2 : w3;
    const int i = (cb & 1023) * 256 + t;
    const float4 vv = ((const float4*)s)[i];
    ushort4 o;
    o.x = f2bf(vv.x);
    o.y = f2bf(vv.y);
    o.z = f2bf(vv.z);
    o.w = f2bf(vv.w);
    ((ushort4*)(wdst + (size_t)y * H * H))[i] = o;
    return;
  }
  const int row = v;
  const float* xr = x + (size_t)row * H;
  float4 vv = ((const float4*)xr)[t];
  float s = vv.x + vv.y + vv.z + vv.w;
  float s2 = vv.x * vv.x + vv.y * vv.y + vv.z * vv.z + vv.w * vv.w;
#pragma unroll
  for (int o = 32; o; o >>= 1) {
    s += __shfl_xor(s, o, 64);
    s2 += __shfl_xor(s2, o, 64);
  }
  const int wave = t >> 6;
  if ((t & 63) == 0) {
    red[wave] = s;
    red[wave + 4] = s2;
  }
  __syncthreads();
  const float ts = red[0] + red[1] + red[2] + red[3];
  const float ts2 = red[4] + red[5] + red[6] + red[7];
  const float mu = ts * (1.0f / (float)H);
  const float var = ts2 * (1.0f / (float)H) - mu * mu;
  const float rstd = rsqrtf(var + 1e-5f);
  const float4 gm = ((const float4*)gamma)[t];
  const float4 bt = ((const float4*)beta)[t];
  ushort4 o;
  o.x = f2bf((vv.x - mu) * rstd * gm.x + bt.x);
  o.y = f2bf((vv.y - mu) * rstd * gm.y + bt.y);
  o.z = f2bf((vv.z - mu) * rstd * gm.z + bt.z);
  o.w = f2bf((vv.w - mu) * rstd * gm.w + bt.w);
  ((ushort4*)(xn + (size_t)row * H))[t] = o;
  __syncthreads(); // protect red[] before next tile's writes
}

// ---------------------------------------------------------------------------
// 128x128x(BK=32) bf16 MFMA GEMM tile (16x16x32, dbuf LDS, 1 barrier/iter,
// XCD-aware id mapping). As/Bs: [2][4096] shorts each.
// ---------------------------------------------------------------------------
template <int EPI, int NPX>
__device__ __forceinline__ void gemm_tile(int id, unsigned short* As, unsigned short* Bs,
                                          const unsigned short* __restrict__ A,
                                          const unsigned short* __restrict__ W,
                                          unsigned short* __restrict__ qk,
                                          unsigned short* __restrict__ vt,
                                          const float* __restrict__ bo,
                                          const float* __restrict__ x,
                                          float* __restrict__ out) {
  const int xcd = id & 7;
  const int r = id >> 3;
  const int nb = xcd * NPX + (r % NPX);
  const int mb = r / NPX;
  const int m0 = mb * 128;
  const int n0 = nb * 128;
  const int tid = threadIdx.x;
  const int wave = tid >> 6;
  const int lane = tid & 63;
  const int l16 = lane & 15;
  const int quad = lane >> 4;
  const int wx = wave & 1, wy = wave >> 1;

  const int sub = lane >> 2;
  const int kcol = (lane & 3) * 8;
  const unsigned short* ag = A + (size_t)(m0 + wave * 32 + sub) * H + kcol;
  const unsigned short* bg = W + (size_t)(n0 + wave * 32 + sub) * H + kcol;
  const int lofs = wave * 32 * 32;

  f32x4 acc[4][4] = {};

  gload16(ag, &As[lofs]);
  gload16(ag + 16 * H, &As[lofs + 16 * 32]);
  gload16(bg, &Bs[lofs]);
  gload16(bg + 16 * H, &Bs[lofs + 16 * 32]);

  for (int it = 0; it < H / 32; it++) {
    const int bi = it & 1;
    __syncthreads();
    if (it + 1 < H / 32) {
      const int k1 = (it + 1) * 32;
      gload16(ag + k1, &As[(bi ^ 1) * 4096 + lofs]);
      gload16(ag + k1 + 16 * H, &As[(bi ^ 1) * 4096 + lofs + 16 * 32]);
      gload16(bg + k1, &Bs[(bi ^ 1) * 4096 + lofs]);
      gload16(bg + k1 + 16 * H, &Bs[(bi ^ 1) * 4096 + lofs + 16 * 32]);
    }
    bf16x8 af[4], bf[4];
#pragma unroll
    for (int t = 0; t < 4; t++) {
      af[t] = *(const bf16x8*)&As[bi * 4096 + (wy * 64 + t * 16 + l16) * 32 + quad * 8];
      bf[t] = *(const bf16x8*)&Bs[bi * 4096 + (wx * 64 + t * 16 + l16) * 32 + quad * 8];
    }
#pragma unroll
    for (int i = 0; i < 4; i++)
#pragma unroll
      for (int j = 0; j < 4; j++)
        acc[i][j] = __builtin_amdgcn_mfma_f32_16x16x32_bf16(af[i], bf[j], acc[i][j], 0, 0, 0);
  }
  __syncthreads(); // LDS reuse safety before caller's next phase/tile

  if (EPI == 0) {
#pragma unroll
    for (int j = 0; j < 4; j++) {
      const int cb = n0 + wx * 64 + j * 16;
      if (cb < 2048) {
        const float qs = (cb < 1024) ? C2_SCALE : 1.0f;
#pragma unroll
        for (int i = 0; i < 4; i++) {
          const int row = m0 + wy * 64 + i * 16 + quad * 4;
#pragma unroll
          for (int r2 = 0; r2 < 4; r2++)
            qk[(size_t)(row + r2) * 2048 + cb + l16] = f2bf(acc[i][j][r2] * qs);
        }
      } else {
        const int n = cb + l16 - 2048; // h*64+d
#pragma unroll
        for (int i = 0; i < 4; i++) {
          const int row0 = m0 + wy * 64 + i * 16 + quad * 4;
          const int b = row0 >> 11;
          const int s = row0 & 2047;
          ushort4 p;
          p.x = f2bf(acc[i][j][0]);
          p.y = f2bf(acc[i][j][1]);
          p.z = f2bf(acc[i][j][2]);
          p.w = f2bf(acc[i][j][3]);
          *(ushort4*)&vt[((size_t)b * 1024 + n) * SEQ + s] = p;
        }
      }
    }
  } else {
#pragma unroll
    for (int j = 0; j < 4; j++) {
      const int col = n0 + wx * 64 + j * 16 + l16;
      const float bv = bo[col];
#pragma unroll
      for (int i = 0; i < 4; i++) {
        const int row = m0 + wy * 64 + i * 16 + quad * 4;
#pragma unroll
        for (int r2 = 0; r2 < 4; r2++) {
          const size_t idx = (size_t)(row + r2) * H + col;
          out[idx] = acc[i][j][r2] + bv + x[idx];
        }
      }
    }
  }
}

// ---------------------------------------------------------------------------
// Flash attention v4.1 tile (proven 54.2 us). Kt/Vt: [2][4096], Pt: [8192].
// ---------------------------------------------------------------------------
__device__ __forceinline__ void attn_tile(int id, unsigned short* Kt, unsigned short* Vt,
                                          unsigned short* Pt,
                                          const unsigned short* __restrict__ qk,
                                          const unsigned short* __restrict__ vt,
                                          unsigned short* __restrict__ O) {
  const int xcd = id & 7;
  const int slot = id >> 3;
  const int qt = slot & 15;
  const int g = slot >> 4;
  const int combo = xcd * 4 + g;
  const int h = combo & 15;
  const int b = combo >> 4;
  const int tid = threadIdx.x;
  const int wave = tid >> 6;
  const int lane = tid & 63;
  const int l16 = lane & 15;
  const int quad = lane >> 4;
  const int l8 = l16 & 7;

  const unsigned short* Qbase = qk + (size_t)b * SEQ * 2048 + h * 64;
  const unsigned short* Kbase = qk + (size_t)b * SEQ * 2048 + 1024 + h * 64;
  const unsigned short* Vbase = vt + ((size_t)b * 1024 + h * 64) * SEQ;

  const int rIn = lane >> 3;
  const int gsw = (lane & 7) ^ rIn;
  const int ch0 = 2 * wave;

  const int qrow0 = qt * 128 + wave * 32 + l16;
  bf16x8 aq[2][2];
#pragma unroll
  for (int u = 0; u < 2; u++)
#pragma unroll
    for (int c = 0; c < 2; c++)
      aq[u][c] = *(const bf16x8*)(Qbase + (size_t)(qrow0 + u * 16) * 2048 + c * 32 + quad * 8);

  float lacc[2][2] = {};
  f32x4 o_acc[2][4] = {};

#pragma unroll
  for (int c = 0; c < 2; c++) {
    const int ch = ch0 + c;
    const int row = ch * 8 + rIn;
    gload16(Kbase + (size_t)row * 2048 + gsw * 8, &Kt[ch * 512]);
    gload16(Vbase + (size_t)row * SEQ + gsw * 8, &Vt[ch * 512]);
  }

  unsigned short* myP0 = &Pt[(wave * 2 + 0) * 1024];
  unsigned short* myP1 = &Pt[(wave * 2 + 1) * 1024];

#pragma unroll 2
  for (int it = 0; it < SEQ / 64; it++) {
    const int bi = it & 1;
    __syncthreads();
    if (it + 1 < SEQ / 64) {
#pragma unroll
      for (int c = 0; c < 2; c++) {
        const int ch = ch0 + c;
        const int row = ch * 8 + rIn;
        gload16(Kbase + (size_t)((it + 1) * 64 + row) * 2048 + gsw * 8,
                &Kt[(bi ^ 1) * 4096 + ch * 512]);
        gload16(Vbase + (size_t)row * SEQ + (it + 1) * 64 + gsw * 8,
                &Vt[(bi ^ 1) * 4096 + ch * 512]);
      }
    }

    f32x4 s[2][4] = {};
#pragma unroll
    for (int c = 0; c < 2; c++) {
#pragma unroll
      for (int t = 0; t < 4; t++) {
        const bf16x8 kf = *(const bf16x8*)&Kt[bi * 4096 + (t * 16 + l16) * 64 +
                                              (((c * 4 + quad) ^ l8) * 8)];
        s[0][t] = __builtin_amdgcn_mfma_f32_16x16x32_bf16(kf, aq[0][c], s[0][t], 0, 0, 0);
        s[1][t] = __builtin_amdgcn_mfma_f32_16x16x32_bf16(kf, aq[1][c], s[1][t], 0, 0, 0);
      }
    }

    float pv[2][4][4];
#pragma unroll
    for (int u = 0; u < 2; u++)
#pragma unroll
      for (int t = 0; t < 4; t++) {
#pragma unroll
        for (int r = 0; r < 4; r++) pv[u][t][r] = fast_exp2(s[u][t][r]);
        lacc[u][t & 1] += (pv[u][t][0] + pv[u][t][1]) + (pv[u][t][2] + pv[u][t][3]);
      }

#pragma unroll
    for (int t = 0; t < 4; t++) {
      const int wofs = l16 * 64 + (((t * 2 + (quad >> 1)) ^ l8) * 8) + (quad & 1) * 4;
      uint2 d0, d1;
      d0.x = pkbf(pv[0][t][0], pv[0][t][1]);
      d0.y = pkbf(pv[0][t][2], pv[0][t][3]);
      d1.x = pkbf(pv[1][t][0], pv[1][t][1]);
      d1.y = pkbf(pv[1][t][2], pv[1][t][3]);
      *(uint2*)&myP0[wofs] = d0;
      *(uint2*)&myP1[wofs] = d1;
    }

#pragma unroll
    for (int c = 0; c < 2; c++) {
      const int rofs = l16 * 64 + (((c * 4 + quad) ^ l8) * 8);
      const bf16x8 pb0 = *(const bf16x8*)&myP0[rofs];
      const bf16x8 pb1 = *(const bf16x8*)&myP1[rofs];
#pragma unroll
      for (int dt = 0; dt < 4; dt++) {
        const bf16x8 vf = *(const bf16x8*)&Vt[bi * 4096 + (dt * 16 + l16) * 64 +
                                              (((c * 4 + quad) ^ l8) * 8)];
        o_acc[0][dt] = __builtin_amdgcn_mfma_f32_16x16x32_bf16(vf, pb0, o_acc[0][dt], 0, 0, 0);
        o_acc[1][dt] = __builtin_amdgcn_mfma_f32_16x16x32_bf16(vf, pb1, o_acc[1][dt], 0, 0, 0);
      }
    }
  }
  __syncthreads(); // LDS reuse safety before caller's next phase

#pragma unroll
  for (int u = 0; u < 2; u++) {
    float l_i = lacc[u][0] + lacc[u][1];
    l_i += __shfl_xor(l_i, 16, 64);
    l_i += __shfl_xor(l_i, 32, 64);
    const float inv = 1.0f / l_i;
    unsigned short* orow = O + ((size_t)(b * SEQ + qrow0 + u * 16)) * H + h * 64;
#pragma unroll
    for (int dt = 0; dt < 4; dt++) {
      uint2 d;
      d.x = pkbf(o_acc[u][dt][0] * inv, o_acc[u][dt][1] * inv);
      d.y = pkbf(o_acc[u][dt][2] * inv, o_acc[u][dt][3] * inv);
      *(uint2*)&orow[dt * 16 + quad * 4] = d;
    }
  }
}

// ---------------------------------------------------------------------------
// Cooperative mega kernel: 4 phases, 3 grid syncs, one launch.
// Grid 512 x 256 (2 blocks/CU: LDS 2x48KB=96<=160, VGPR bound (256,2) loose).
// ---------------------------------------------------------------------------
__global__ __launch_bounds__(256, 2) void mega_kernel(
    const float* __restrict__ x, const float* __restrict__ Wq,
    const float* __restrict__ Wk, const float* __restrict__ Wv,
    const float* __restrict__ Wo, const float* __restrict__ bo,
    const float* __restrict__ gamma, const float* __restrict__ beta,
    unsigned short* __restrict__ xn, unsigned short* __restrict__ wcat,
    unsigned short* __restrict__ qkb, unsigned short* __restrict__ vtb,
    unsigned short* __restrict__ atb, float* __restrict__ out) {
  __shared__ __align__(16) unsigned short smem[24576]; // 48 KB union
  __shared__ float red[8];
  cg::grid_group grid = cg::this_grid();
  const int bid = blockIdx.x;

  // Phase 0: LayerNorm (0..4095) + weight cast (4096..8191)
  for (int v = bid; v < M_TOT + 4096; v += NCOOP)
    lncast_tile(v, red, x, gamma, beta, xn, Wq, Wk, Wv, Wo, wcat);
  grid.sync();

  // Phase 1: QKV GEMM, 768 tiles over 512 blocks
  for (int tile = bid; tile < 768; tile += NCOOP)
    gemm_tile<0, 3>(tile, smem, smem + 8192, xn, wcat, qkb, vtb, nullptr, nullptr,
                    nullptr);
  grid.sync();

  // Phase 2: attention, 512 tiles
  attn_tile(bid, smem, smem + 8192, smem + 16384, qkb, vtb, atb);
  grid.sync();

  // Phase 3: proj GEMM + bias + residual, 256 tiles
  if (bid < 256)
    gemm_tile<1, 1>(bid, smem, smem + 8192, atb, wcat + (size_t)3 * H * H, nullptr,
                    nullptr, bo, x, out);
}

// ---------------------------------------------------------------------------
// Fallback kernels (round-8 proven path) built on the same tile bodies.
// ---------------------------------------------------------------------------
__global__ __launch_bounds__(256) void ln_cast_kernel(const float* __restrict__ x,
                                                      const float* __restrict__ gamma,
                                                      const float* __restrict__ beta,
                                                      unsigned short* __restrict__ xn,
                                                      const float* __restrict__ w0,
                                                      const float* __restrict__ w1,
                                                      const float* __restrict__ w2,
                                                      const float* __restrict__ w3,
                                                      unsigned short* __restrict__ wdst) {
  __shared__ float red[8];
  lncast_tile(blockIdx.x, red, x, gamma, beta, xn, w0, w1, w2, w3, wdst);
}

template <int EPI, int NPX>
__global__ __launch_bounds__(256, 4) void gemm128(const unsigned short* __restrict__ A,
                                                  const unsigned short* __restrict__ W,
                                                  unsigned short* __restrict__ qk,
                                                  unsigned short* __restrict__ vt,
                                                  const float* __restrict__ bo,
                                                  const float* __restrict__ x,
                                                  float* __restrict__ out) {
  __shared__ __align__(16) unsigned short As[2 * 4096];
  __shared__ __align__(16) unsigned short Bs[2 * 4096];
  gemm_tile<EPI, NPX>(blockIdx.x, As, Bs, A, W, qk, vt, bo, x, out);
}

__global__ __launch_bounds__(256, 2) void attn_kernel(const unsigned short* __restrict__ qk,
                                                      const unsigned short* __restrict__ vt,
                                                      unsigned short* __restrict__ O) {
  __shared__ __align__(16) unsigned short Kt[2 * 4096];
  __shared__ __align__(16) unsigned short Vt[2 * 4096];
  __shared__ __align__(16) unsigned short Pt[8192];
  attn_tile(blockIdx.x, Kt, Vt, Pt, qk, vt, O);
}

// ---------------------------------------------------------------------------
extern "C" void kernel_launch(void* const* d_in, const int* in_sizes, int n_in,
                              void* d_out, int out_size, void* d_ws, size_t ws_size,
                              hipStream_t stream) {
  const float* x = (const float*)d_in[0];
  const float* Wq = (const float*)d_in[1];
  const float* Wk = (const float*)d_in[2];
  const float* Wv = (const float*)d_in[3];
  const float* Wv_ = Wv;
  const float* Wo = (const float*)d_in[4];
  const float* bo = (const float*)d_in[5];
  const float* gamma = (const float*)d_in[6];
  const float* beta = (const float*)d_in[7];
  float* out = (float*)d_out;
  (void)Wv_;

  unsigned short* ws = (unsigned short*)d_ws;
  unsigned short* xn = ws;                              // 4096*1024
  unsigned short* wcat = xn + (size_t)M_TOT * H;        // 4*1024*1024 (Wq,Wk,Wv,Wo)
  unsigned short* qkb = wcat + (size_t)4 * H * H;       // 4096*2048 (Q | K)
  unsigned short* vtb = qkb + (size_t)M_TOT * 2048;     // 2*1024*2048 (V^T)
  unsigned short* atb = vtb + (size_t)BATCH * H * SEQ;  // 4096*1024

  void* args[] = {&x, &Wq, &Wk, &Wv, &Wo, &bo, &gamma, &beta,
                  &xn, &wcat, &qkb, &vtb, &atb, &out};
  hipError_t e = hipLaunchCooperativeKernel((const void*)mega_kernel, dim3(NCOOP),
                                            dim3(256), args, 0, stream);
  if (e != hipSuccess) {
    (void)hipGetLastError(); // clear sticky error, use proven 4-kernel path
    ln_cast_kernel<<<M_TOT + 4096, 256, 0, stream>>>(x, gamma, beta, xn, Wq, Wk, Wv, Wo,
                                                     wcat);
    gemm128<0, 3><<<(M_TOT / 128) * (NQKV / 128), 256, 0, stream>>>(
        xn, wcat, qkb, vtb, nullptr, nullptr, nullptr);
    attn_kernel<<<(SEQ / 128) * NHEAD * BATCH, 256, 0, stream>>>(qkb, vtb, atb);
    gemm128<1, 1><<<(M_TOT / 128) * (H / 128), 256, 0, stream>>>(
        atb, wcat + (size_t)3 * H * H, nullptr, nullptr, bo, x, out);
  }
}